// Round 19
// baseline (265.360 us; speedup 1.0000x reference)
//
#include <hip/hip_runtime.h>
#include <math.h>

#define B_SZ 1024
#define IN_SZ 2048
#define H0_SZ 4096
#define H1_SZ 4096
#define OUT_SZ 1000

typedef _Float16 f16;
typedef __attribute__((ext_vector_type(4))) _Float16 f16x4;
typedef __attribute__((ext_vector_type(8))) _Float16 f16x8;
typedef __attribute__((ext_vector_type(4))) float f32x4;

// ---------------- ws layout (bytes) ----------------
#define OFF_N0     0ULL
#define OFF_N1     4ULL
#define OFF_MSUM0  256ULL
#define OFF_MSUM1  4352ULL
#define OFF_CPOS0  8448ULL
#define OFF_CPOS1  24832ULL
#define OFF_IDX0   41216ULL
#define OFF_IDX1   57600ULL
#define OFF_PXZ    73984ULL      // 256 dbl
#define OFF_PFL    82176ULL      // 2048 dbl (0..255 flow0, 1024..1279 flow1)
#define OFF_PCE    98560ULL      // 1024 dbl
#define OFF_PB     106752ULL     // 32x4 dbl
#define OFF_PW     107776ULL     // 8192x4 dbl (0..1023 W0, 4096..5119 W1)
#define OFF_BS0    370688ULL
#define OFF_BS1    387072ULL
#define OFF_BSO    403456ULL
#define OFF_XH     407552ULL
#define OFF_XL     4601856ULL
#define OFF_H0H    8796160ULL
#define OFF_H0L    17184768ULL
#define OFF_H1H    25573376ULL
#define OFF_H1L    33961984ULL
#define OFF_W0CH   42350592ULL   // w0 FULL plane [4096][2048] f16 = 16,777,216B exactly
#define OFF_W0CL   59127808ULL   // FREE span
#define OFF_W1CH   75905024ULL
#define OFF_W1CL   109459456ULL  // FREE span
#define OFF_WOCH   143013888ULL
#define OFF_WOCL   151402496ULL  // FREE span
#define OFF_PART   159791104ULL

#define PSTRIDE_H  2560
#define PSTRIDE_O  1024

// pre0 roles: idx(2) W0full(1024x4) splitx(256) flow0(256) flow1(256) b0(16) b1(16) bO(4)
#define P0_IDX  2
#define P0_W0   1026
#define P0_SX   1282
#define P0_FL0  1538
#define P0_FL1  1794
#define P0_B0   1810
#define P0_B1   1826
#define P0_BO   1830
// L0-fused roles: gemm(1280) W1(1024x4)
#define L0_G    1280
#define L0_W1   2304
// L1-fused roles: gemm(1280) Wo(250x4)
#define L1_G    1280
#define L1_WO   1530

__device__ __forceinline__ void gload_lds16(const void* g, void* l)
{
    __builtin_amdgcn_global_load_lds((const __attribute__((address_space(1))) void*)g,
                                     (__attribute__((address_space(3))) void*)l, 16, 0, 0);
}

__device__ __forceinline__ void reduce4_store(double v0, double v1, double v2, double v3,
                                              double* dst)
{
    __shared__ double sh[4][4];
    double v[4] = {v0, v1, v2, v3};
    int lane = threadIdx.x & 63, wid = threadIdx.x >> 6;
#pragma unroll
    for (int a = 0; a < 4; ++a) {
        double x = v[a];
#pragma unroll
        for (int o = 32; o > 0; o >>= 1) x += __shfl_down(x, o, 64);
        if (lane == 0) sh[a][wid] = x;
    }
    __syncthreads();
    if (threadIdx.x == 0) {
        dst[0] = sh[0][0] + sh[0][1] + sh[0][2] + sh[0][3];
        dst[1] = sh[1][0] + sh[1][1] + sh[1][2] + sh[1][3];
        dst[2] = sh[2][0] + sh[2][1] + sh[2][2] + sh[2][3];
        dst[3] = sh[3][0] + sh[3][1] + sh[3][2] + sh[3][3];
    }
}

__device__ __forceinline__ void reduce1_store(double v, double* dst)
{
    __shared__ double sh1[4];
    int lane = threadIdx.x & 63, wid = threadIdx.x >> 6;
#pragma unroll
    for (int o = 32; o > 0; o >>= 1) v += __shfl_down(v, o, 64);
    if (lane == 0) sh1[wid] = v;
    __syncthreads();
    if (threadIdx.x == 0) dst[0] = sh1[0] + sh1[1] + sh1[2] + sh1[3];
}

// ---- compaction map build as a 256-thread role (r18-verified)
__device__ void role_idx256(int pass,
                            const int* __restrict__ mask0, const int* __restrict__ mask1,
                            int* __restrict__ cpos0, int* __restrict__ idx0, int* __restrict__ n0,
                            int* __restrict__ cpos1, int* __restrict__ idx1, int* __restrict__ n1)
{
    __shared__ int sh[256];
    const int t = threadIdx.x;
    const int* mask = pass ? mask1 : mask0;
    int* cpos = pass ? cpos1 : cpos0;
    int* idx = pass ? idx1 : idx0;
    int* np = pass ? n1 : n0;
    const int4* m4 = (const int4*)mask;
    int4 q[4];
#pragma unroll
    for (int jj = 0; jj < 4; ++jj) q[jj] = m4[t * 4 + jj];
    int s = 0;
#pragma unroll
    for (int jj = 0; jj < 4; ++jj) s += q[jj].x + q[jj].y + q[jj].z + q[jj].w;
    sh[t] = s;
    __syncthreads();
    for (int o = 1; o < 256; o <<= 1) {
        int v = (t >= o) ? sh[t - o] : 0;
        __syncthreads();
        sh[t] += v;
        __syncthreads();
    }
    int run = sh[t] - s;
#pragma unroll
    for (int jj = 0; jj < 4; ++jj) {
        int4 m = q[jj];
        int4 cp;
        cp.x = run; cp.y = run + m.x; cp.z = cp.y + m.y; cp.w = cp.z + m.z;
        ((int4*)cpos)[t * 4 + jj] = cp;
        const int e = 16 * t + 4 * jj;
        if (m.x) idx[cp.x] = e + 0;
        if (m.y) idx[cp.y] = e + 1;
        if (m.z) idx[cp.z] = e + 2;
        if (m.w) idx[cp.w] = e + 3;
        run = cp.w + m.w;
    }
    if (t == 255) *np = sh[255];
}

// ================= role bodies =========

__device__ void role_splitx(int rb, const float4* x, const float4* zw,
                            f16x4* xh, f16x4* xl, double* pxz)
{
    const int n4 = B_SZ * IN_SZ / 4;
    double s = 0;
    int i = rb * 256 + threadIdx.x;
    const int stride = 256 * 256;
    for (; i < n4; i += stride) {
        float4 v = x[i];
        float4 z = zw[i & (IN_SZ / 4 - 1)];
        s += (double)((v.x * z.x + v.y * z.y) + (v.z * z.z + v.w * z.w));
        f16 h0 = (f16)v.x, h1 = (f16)v.y, h2 = (f16)v.z, h3 = (f16)v.w;
        f16x4 hv = {h0, h1, h2, h3};
        f16x4 lv = {(f16)(v.x - (float)h0), (f16)(v.y - (float)h1),
                    (f16)(v.z - (float)h2), (f16)(v.w - (float)h3)};
        xh[i] = hv; xl[i] = lv;
    }
    reduce1_store(s, pxz + rb);
}

__device__ void role_flow4(int bb, const int* mz, const float* pfz, const int* maskmu,
                           float* msum, double* pfl)
{
    const int w = threadIdx.x >> 6, lane = threadIdx.x & 63;
    const int r = bb * 4 + w;
    const int4* m4 = (const int4*)(mz + (size_t)r * 4096);
    const float4* p4 = (const float4*)(pfz + (size_t)r * 4096);
    const int4* k4 = (const int4*)maskmu;
    int s = 0;
    double fl = 0;
    for (int i = lane; i < 1024; i += 64) {
        int4 m = m4[i];
        float4 p = p4[i];
        int4 k = k4[i];
        s += m.x * k.x + m.y * k.y + m.z * k.z + m.w * k.w;
        float a0 = fminf(fmaxf(p.x, 1e-6f), 1.0f - 1e-6f);
        float a1 = fminf(fmaxf(p.y, 1e-6f), 1.0f - 1e-6f);
        float a2 = fminf(fmaxf(p.z, 1e-6f), 1.0f - 1e-6f);
        float a3 = fminf(fmaxf(p.w, 1e-6f), 1.0f - 1e-6f);
        float g0 = logf(m.x ? a0 : 1.0f - a0);
        float g1 = logf(m.y ? a1 : 1.0f - a1);
        float g2 = logf(m.z ? a2 : 1.0f - a2);
        float g3 = logf(m.w ? a3 : 1.0f - a3);
        fl += (double)((g0 + g1) + (g2 + g3));
    }
#pragma unroll
    for (int o = 32; o > 0; o >>= 1) s += __shfl_down(s, o, 64);
    if (lane == 0) msum[r] = (float)s;
    reduce1_store(fl, pfl + bb);
}

template <int RED>
__device__ void role_bsample(int rb, const float* bmu, const float* bls, const float* beps,
                             float* out, int n, double* pb)
{
    int i = rb * 256 + threadIdx.x;
    float l = 0.f, e = 0.f;
    if (i < n) {
        l = bls[i]; e = beps[i];
        out[i] = fmaf(__expf(l), e, bmu[i]);
    }
    if (RED) {
        double sls = (i < n) ? (double)l : 0.0;
        double se2 = (i < n) ? (double)e * e : 0.0;
        reduce4_store(sls, se2, 0.0, 0.0, pb + (size_t)rb * 4);
    }
}

// W0 FULL sample (no compaction, no mask dependency): 4 rows/block, coalesced stores
__device__ void role_w0f4(int bb, const float* mu, const float* ls, const float* eps,
                          f16* hi, double* pw)
{
    double sls = 0, se2 = 0, smu2 = 0, sex = 0;
#pragma unroll
    for (int rr = 0; rr < 4; ++rr) {
        const int r = bb * 4 + rr;
        const size_t rbb = (size_t)r * IN_SZ;
        const float4* m4 = (const float4*)(mu + rbb);
        const float4* l4 = (const float4*)(ls + rbb);
        const float4* e4 = (const float4*)(eps + rbb);
        f16* hrow = hi + (size_t)r * IN_SZ;
        for (int i = threadIdx.x; i < IN_SZ / 4; i += 256) {
            float4 m = m4[i], l = l4[i], e = e4[i];
            float g0 = __expf(l.x), g1 = __expf(l.y), g2 = __expf(l.z), g3 = __expf(l.w);
            float w0 = fmaf(g0, e.x, m.x), w1 = fmaf(g1, e.y, m.y);
            float w2 = fmaf(g2, e.z, m.z), w3 = fmaf(g3, e.w, m.w);
            sls += (double)((l.x + l.y) + (l.z + l.w));
            se2 += (double)((e.x * e.x + e.y * e.y) + (e.z * e.z + e.w * e.w));
            smu2 += (double)((m.x * m.x + m.y * m.y) + (m.z * m.z + m.w * m.w));
            sex += (double)((g0 + g1) + (g2 + g3));
            f16x4 hv = {(f16)w0, (f16)w1, (f16)w2, (f16)w3};
            *(f16x4*)(hrow + i * 4) = hv;
        }
    }
    reduce4_store(sls, se2, smu2, sex, pw + (size_t)bb * 4);
}

template <int ROWC, int RED>
__device__ void role_colc4(int bb, const float* mu, const float* ls, const float* eps,
                           const int* maskR, const int* cposR,
                           const int* maskC, const int* cposC, const int* pNc,
                           f16* hi, double* pw, f16* ldsH)
{
    const int t = threadIdx.x;
    const f16x8 z8 = {0, 0, 0, 0, 0, 0, 0, 0};
    for (int i = t; i < 512; i += 256) ((f16x8*)ldsH)[i] = z8;
    __syncthreads();
    double sls = 0, se2 = 0, smu2 = 0, sex = 0;
    const int n8 = ((*pNc + 127) >> 7) << 4;
#pragma unroll
    for (int rr = 0; rr < 4; ++rr) {
        const int r = bb * 4 + rr;
        const size_t rbb = (size_t)r * 4096;
        const float4* m4 = (const float4*)(mu + rbb);
        const float4* l4 = (const float4*)(ls + rbb);
        const float4* e4 = (const float4*)(eps + rbb);
        const bool wr_ = ROWC ? (maskR[r] != 0) : true;
        const int drow = ROWC ? cposR[r] : r;
        for (int i = t; i < 1024; i += 256) {
            float4 m = m4[i], l = l4[i], e = e4[i];
            float g0 = __expf(l.x), g1 = __expf(l.y), g2 = __expf(l.z), g3 = __expf(l.w);
            float w0 = fmaf(g0, e.x, m.x), w1 = fmaf(g1, e.y, m.y);
            float w2 = fmaf(g2, e.z, m.z), w3 = fmaf(g3, e.w, m.w);
            if (RED) {
                sls += (double)((l.x + l.y) + (l.z + l.w));
                se2 += (double)((e.x * e.x + e.y * e.y) + (e.z * e.z + e.w * e.w));
                smu2 += (double)((m.x * m.x + m.y * m.y) + (m.z * m.z + m.w * m.w));
                sex += (double)((g0 + g1) + (g2 + g3));
            }
            if (wr_) {
                int4 mc = ((const int4*)maskC)[i];
                int4 cp = ((const int4*)cposC)[i];
                if (mc.x) ldsH[cp.x] = (f16)w0;
                if (mc.y) ldsH[cp.y] = (f16)w1;
                if (mc.z) ldsH[cp.z] = (f16)w2;
                if (mc.w) ldsH[cp.w] = (f16)w3;
            }
        }
        __syncthreads();
        if (wr_) {
            f16x8* hd = (f16x8*)(hi + (size_t)drow * 4096);
            for (int i = t; i < n8; i += 256) hd[i] = ((const f16x8*)ldsH)[i];
        }
        __syncthreads();
    }
    if (RED) reduce4_store(sls, se2, smu2, sex, pw + (size_t)bb * 4);
}

// ---- 2-product GEMM body: 64(M)x128(N) tile, BK=32, 4 waves, 2x16KB LDS dbuf,
// optional W row-gather via widx (per-lane global source addr). Same verified
// 16-row-chunk primitive: chunk layout (row=cidx*16+(l&15), k=(l>>4)*8), frag read
// chunk*512+lane*8, C map col = bn+(wc*4+n)*16+l15, row = bm+(wr*2+m)*16+l4*4+j.
template <int NSPLIT>
__device__ void gemm_body(int bid, f16* ldsbase,
                          const f16* Ah, const f16* Al, int SA,
                          const f16* Wh, int SW, const int* widx,
                          const int* pN, int NFIX, const int* pK, int KFIX,
                          float* P0, float* P1, float* P2, float* P3,
                          float* P4, float* P5, float* P6, float* P7, int pstride)
{
    const int c8 = bid & 7, j = bid >> 3;
    int nt, mt, z;
    if (NSPLIT == 4) {
        const int p = c8 + 8 * (j % 10);
        nt = p >> 2; z = p & 3; mt = j / 10;      // j 0..159 -> mt 0..15
    } else {
        const int p = c8 + 8 * (j & 7);
        nt = p >> 3; z = p & 7; mt = j >> 3;      // j 0..127 -> mt 0..15
    }
    const int nvalid = pN ? *pN : NFIX;
    const int bn = nt * 128;
    if (bn >= nvalid) return;
    const int bm = mt * 64;
    const int kvalid = pK ? *pK : KFIX;
    const int ktiles = (kvalid + 31) >> 5;
    const int prt = (ktiles + NSPLIT - 1) / NSPLIT;
    const int kt0 = z * prt;
    const int kt1 = min(ktiles, kt0 + prt);
    float* Cf = (z == 0) ? P0 : (z == 1) ? P1 : (z == 2) ? P2 : (z == 3) ? P3
              : (z == 4) ? P4 : (z == 5) ? P5 : (z == 6) ? P6 : P7;

    const int tid = threadIdx.x;
    const int wv = tid >> 6, lane = tid & 63;
    const int wr = wv >> 1, wc = wv & 1;
    const int l15 = lane & 15, l4 = lane >> 4;

    // 16 chunks: 0-3 A-hi (64 rows), 4-7 A-lo, 8-15 W (128 rows); wave stages 4
    const f16* sg[4];
    int ldst[4];
#pragma unroll
    for (int i = 0; i < 4; ++i) {
        const int c = wv * 4 + i;
        const f16* base; int rowb, S_, cidx, isW;
        if (c < 4)      { base = Ah; rowb = bm; S_ = SA; cidx = c;     isW = 0; }
        else if (c < 8) { base = Al; rowb = bm; S_ = SA; cidx = c - 4; isW = 0; }
        else            { base = Wh; rowb = bn; S_ = SW; cidx = c - 8; isW = 1; }
        int row = rowb + cidx * 16 + l15;
        if (isW && widx) row = (row < nvalid) ? widx[row] : 0;
        sg[i] = base + (size_t)row * S_ + l4 * 8;
        ldst[i] = c * 512 + lane * 8;
    }

#define STAGE(KT, B) do { \
        _Pragma("unroll") \
        for (int i_ = 0; i_ < 4; ++i_) \
            gload_lds16(sg[i_] + (size_t)(KT) * 32, ldsbase + (B) * 8192 + ldst[i_]); \
    } while (0)

    f32x4 acc[2][4];
#pragma unroll
    for (int m = 0; m < 2; ++m)
#pragma unroll
        for (int n = 0; n < 4; ++n) acc[m][n] = (f32x4){0.f, 0.f, 0.f, 0.f};

    if (kt0 < kt1) {
        STAGE(kt0, 0);
        int cur = 0;
        for (int kt = kt0; kt < kt1; ++kt) {
            asm volatile("s_waitcnt vmcnt(0)" ::: "memory");
            __builtin_amdgcn_s_barrier();
            __builtin_amdgcn_sched_barrier(0);
            if (kt + 1 < kt1) STAGE(kt + 1, cur ^ 1);
            __builtin_amdgcn_sched_barrier(0);
            const f16* L = ldsbase + cur * 8192;
            f16x8 ah[2], al[2], wh[4];
#pragma unroll
            for (int m = 0; m < 2; ++m) {
                ah[m] = *(const f16x8*)(L + (wr * 2 + m) * 512 + lane * 8);
                al[m] = *(const f16x8*)(L + 2048 + (wr * 2 + m) * 512 + lane * 8);
            }
#pragma unroll
            for (int n = 0; n < 4; ++n)
                wh[n] = *(const f16x8*)(L + 4096 + (wc * 4 + n) * 512 + lane * 8);
            __builtin_amdgcn_s_setprio(1);
#pragma unroll
            for (int m = 0; m < 2; ++m)
#pragma unroll
                for (int n = 0; n < 4; ++n)
                    acc[m][n] = __builtin_amdgcn_mfma_f32_16x16x32_f16(ah[m], wh[n], acc[m][n], 0, 0, 0);
#pragma unroll
            for (int m = 0; m < 2; ++m)
#pragma unroll
                for (int n = 0; n < 4; ++n)
                    acc[m][n] = __builtin_amdgcn_mfma_f32_16x16x32_f16(al[m], wh[n], acc[m][n], 0, 0, 0);
            __builtin_amdgcn_s_setprio(0);
            cur ^= 1;
        }
    }
#undef STAGE

#pragma unroll
    for (int n = 0; n < 4; ++n) {
        const int c = bn + wc * 64 + n * 16 + l15;
        if (c >= pstride) continue;
#pragma unroll
        for (int m = 0; m < 2; ++m)
#pragma unroll
            for (int j2 = 0; j2 < 4; ++j2) {
                const int row = bm + wr * 32 + m * 16 + l4 * 4 + j2;
                Cf[(size_t)row * pstride + c] = acc[m][n][j2];
            }
    }
}

// ---- pre0: idxbuild + W0 full sample + all idx-independent streaming
__global__ __launch_bounds__(256) void pre0_kernel(
    const float* __restrict__ x, const float* __restrict__ zw,
    const float* __restrict__ wmu0, const float* __restrict__ wls0, const float* __restrict__ weps0,
    const float* __restrict__ bmu0, const float* __restrict__ bls0, const float* __restrict__ beps0,
    const float* __restrict__ bmu1, const float* __restrict__ bls1, const float* __restrict__ beps1,
    const float* __restrict__ bmuo, const float* __restrict__ blso, const float* __restrict__ bepso,
    const float* __restrict__ pfz0, const float* __restrict__ pfz1,
    const int* __restrict__ mz0, const int* __restrict__ mz1,
    const int* __restrict__ mmu0, const int* __restrict__ mmu1,
    int* __restrict__ cpos0, int* __restrict__ idx0, int* __restrict__ n0p,
    int* __restrict__ cpos1, int* __restrict__ idx1, int* __restrict__ n1p,
    f16* __restrict__ xh, f16* __restrict__ xl, f16* __restrict__ w0full,
    float* __restrict__ bs0, float* __restrict__ bs1, float* __restrict__ bso,
    float* __restrict__ msum0, float* __restrict__ msum1,
    double* __restrict__ PXZ, double* __restrict__ PFL,
    double* __restrict__ PB, double* __restrict__ PW)
{
    const int b = blockIdx.x;
    if (b < P0_IDX) {
        role_idx256(b, mmu0, mmu1, cpos0, idx0, n0p, cpos1, idx1, n1p);
    } else if (b < P0_W0) {
        role_w0f4(b - P0_IDX, wmu0, wls0, weps0, w0full, PW);
    } else if (b < P0_SX) {
        role_splitx(b - P0_W0, (const float4*)x, (const float4*)zw,
                    (f16x4*)xh, (f16x4*)xl, PXZ);
    } else if (b < P0_FL0) {
        role_flow4(b - P0_SX, mz0, pfz0, mmu0, msum0, PFL);
    } else if (b < P0_FL1) {
        role_flow4(b - P0_FL0, mz1, pfz1, mmu1, msum1, PFL + 1024);
    } else if (b < P0_B0) {
        role_bsample<1>(b - P0_FL1, bmu0, bls0, beps0, bs0, H0_SZ, PB);
    } else if (b < P0_B1) {
        role_bsample<1>(b - P0_B0, bmu1, bls1, beps1, bs1, H1_SZ, PB + 16 * 4);
    } else {
        role_bsample<0>(b - P0_B1, bmuo, blso, bepso, bso, OUT_SZ, nullptr);
    }
}

// ---- L0 GEMM (W row-gather via idx0) fused with W1 sample
__global__ __launch_bounds__(256, 5) void gemmL0_kernel(
    const f16* __restrict__ xh, const f16* __restrict__ xl, const f16* __restrict__ w0full,
    const int* __restrict__ idx0, const int* __restrict__ n0p,
    float* __restrict__ A0, float* __restrict__ A1,
    float* __restrict__ A2, float* __restrict__ A3,
    const float* __restrict__ wmu1, const float* __restrict__ wls1, const float* __restrict__ weps1,
    const int* __restrict__ mmu0, const int* __restrict__ mmu1,
    const int* __restrict__ cpos0, const int* __restrict__ cpos1,
    f16* __restrict__ w1ch, double* __restrict__ PW)
{
    __shared__ __align__(16) f16 lds[2][8192];
    const int b = blockIdx.x;
    if (b < L0_G) {
        gemm_body<4>(b, &lds[0][0], xh, xl, IN_SZ, w0full, IN_SZ, idx0,
                     n0p, 0, nullptr, IN_SZ,
                     A0, A1, A2, A3, nullptr, nullptr, nullptr, nullptr, PSTRIDE_H);
    } else {
        role_colc4<1, 1>(b - L0_G, wmu1, wls1, weps1, mmu1, cpos1, mmu0, cpos0, n0p,
                         w1ch, PW + (size_t)4096 * 4, &lds[0][0]);
    }
}

// ---- L1 GEMM fused with Wo sample
__global__ __launch_bounds__(256, 5) void gemmL1_kernel(
    const f16* __restrict__ h0h, const f16* __restrict__ h0l, const f16* __restrict__ w1ch,
    const int* __restrict__ n1p, const int* __restrict__ n0p,
    float* __restrict__ B0, float* __restrict__ B1,
    float* __restrict__ B2, float* __restrict__ B3,
    const float* __restrict__ wmuo, const float* __restrict__ wlso, const float* __restrict__ wepso,
    const int* __restrict__ mmu1, const int* __restrict__ cpos1,
    f16* __restrict__ woch)
{
    __shared__ __align__(16) f16 lds[2][8192];
    const int b = blockIdx.x;
    if (b < L1_G) {
        gemm_body<4>(b, &lds[0][0], h0h, h0l, 4096, w1ch, 4096, nullptr,
                     n1p, 0, n0p, 0,
                     B0, B1, B2, B3, nullptr, nullptr, nullptr, nullptr, PSTRIDE_H);
    } else {
        role_colc4<0, 0>(b - L1_G, wmuo, wlso, wepso, nullptr, nullptr, mmu1, cpos1, n1p,
                         woch, nullptr, &lds[0][0]);
    }
}

// ---- Lo GEMM (split-K8)
__global__ __launch_bounds__(256, 5) void gemmLo_kernel(
    const f16* __restrict__ h1h, const f16* __restrict__ h1l, const f16* __restrict__ woch,
    const int* __restrict__ n1p,
    float* __restrict__ Q0, float* __restrict__ Q1, float* __restrict__ Q2, float* __restrict__ Q3,
    float* __restrict__ Q4, float* __restrict__ Q5, float* __restrict__ Q6, float* __restrict__ Q7)
{
    __shared__ __align__(16) f16 lds[2][8192];
    gemm_body<8>(blockIdx.x, &lds[0][0], h1h, h1l, 4096, woch, 4096, nullptr,
                 nullptr, OUT_SZ, n1p, 0,
                 Q0, Q1, Q2, Q3, Q4, Q5, Q6, Q7, PSTRIDE_O);
}

// ---- combine 4 split-K partials + bias + leaky + mask -> h hi/lo planes
__global__ __launch_bounds__(256) void combine4_kernel(
    const float* __restrict__ PA, const float* __restrict__ PB,
    const float* __restrict__ PC, const float* __restrict__ PD, int pstride,
    const float* __restrict__ bsamp, const int* __restrict__ idx,
    const int* __restrict__ mz, const float* __restrict__ msum,
    const int* __restrict__ pN,
    f16* __restrict__ Chh, f16* __restrict__ Chl)
{
    const int nv = *pN;
    const int bn = blockIdx.x * 64;
    const int bm = blockIdx.y * 64;
    const int t = threadIdx.x;
    const int c0 = bn + (t & 15) * 4;
    const int r0 = bm + (t >> 4);
#pragma unroll
    for (int rr = 0; rr < 4; ++rr) {
        const int row = r0 + rr * 16;
        const float mult = 4096.0f / (msum[row] + 1e-6f);
        float sv[4] = {0.f, 0.f, 0.f, 0.f};
        if (c0 < pstride) {
            float4 a = *(const float4*)(PA + (size_t)row * pstride + c0);
            float4 b = *(const float4*)(PB + (size_t)row * pstride + c0);
            float4 c = *(const float4*)(PC + (size_t)row * pstride + c0);
            float4 d = *(const float4*)(PD + (size_t)row * pstride + c0);
            sv[0] = (a.x + b.x) + (c.x + d.x);
            sv[1] = (a.y + b.y) + (c.y + d.y);
            sv[2] = (a.z + b.z) + (c.z + d.z);
            sv[3] = (a.w + b.w) + (c.w + d.w);
        }
        f16 hh[4], ll[4];
#pragma unroll
        for (int jj = 0; jj < 4; ++jj) {
            const int c = c0 + jj;
            float v = 0.f;
            if (c < nv) {
                const int orig = idx[c];
                v = sv[jj] + bsamp[orig];
                v = v >= 0.f ? v : 0.01f * v;
                v = v * (float)mz[(size_t)row * 4096 + orig] * mult;
            }
            hh[jj] = (f16)v;
            ll[jj] = (f16)(v - (float)hh[jj]);
        }
        f16x4 hv = {hh[0], hh[1], hh[2], hh[3]};
        f16x4 lv = {ll[0], ll[1], ll[2], ll[3]};
        *(f16x4*)(Chh + (size_t)row * 4096 + c0) = hv;
        *(f16x4*)(Chl + (size_t)row * 4096 + c0) = lv;
    }
}

// ---- CE over 8 split-K partials + sampled bias
__global__ __launch_bounds__(256) void ce_fused8_kernel(
    const float* __restrict__ Q0, const float* __restrict__ Q1,
    const float* __restrict__ Q2, const float* __restrict__ Q3,
    const float* __restrict__ Q4, const float* __restrict__ Q5,
    const float* __restrict__ Q6, const float* __restrict__ Q7,
    const float* __restrict__ bso, const int* __restrict__ y,
    float* __restrict__ pred, double* __restrict__ pce)
{
    const int b = blockIdx.x;
    float mx = -1e30f;
    for (int jj = threadIdx.x; jj < OUT_SZ; jj += 256) {
        const size_t o = (size_t)b * PSTRIDE_O + jj;
        float v = ((Q0[o] + Q1[o]) + (Q2[o] + Q3[o]))
                + ((Q4[o] + Q5[o]) + (Q6[o] + Q7[o])) + bso[jj];
        pred[(size_t)b * OUT_SZ + jj] = v;
        mx = fmaxf(mx, v);
    }
#pragma unroll
    for (int o = 32; o > 0; o >>= 1) mx = fmaxf(mx, __shfl_down(mx, o, 64));
    __shared__ float sm[4];
    if ((threadIdx.x & 63) == 0) sm[threadIdx.x >> 6] = mx;
    __syncthreads();
    mx = fmaxf(fmaxf(sm[0], sm[1]), fmaxf(sm[2], sm[3]));
    double se = 0;
    for (int jj = threadIdx.x; jj < OUT_SZ; jj += 256)
        se += (double)__expf(pred[(size_t)b * OUT_SZ + jj] - mx);
#pragma unroll
    for (int o = 32; o > 0; o >>= 1) se += __shfl_down(se, o, 64);
    __shared__ double sd[4];
    if ((threadIdx.x & 63) == 0) sd[threadIdx.x >> 6] = se;
    __syncthreads();
    if (threadIdx.x == 0) {
        double lse = (double)mx + log(sd[0] + sd[1] + sd[2] + sd[3]);
        pce[b] = lse - (double)pred[(size_t)b * OUT_SZ + y[b]];
    }
}

// ---- final reduction + loss assembly
__global__ __launch_bounds__(256) void finalize_kernel(
    const double* __restrict__ PXZ, const double* __restrict__ PFL,
    const double* __restrict__ PCE, const double* __restrict__ PB,
    const double* __restrict__ PW, const int* __restrict__ dss, float* __restrict__ out)
{
    const int t = threadIdx.x;
    double xz = 0, fl = 0, ce = 0, ls = 0, e2 = 0, mu2 = 0, ex = 0;
    xz += PXZ[t];
    fl += PFL[t] + PFL[1024 + t];
    for (int i = t; i < 1024; i += 256) ce += PCE[i];
    for (int i = t; i < 1024; i += 256) {
        const double* p0 = PW + (size_t)i * 4;
        const double* p1 = PW + (size_t)(4096 + i) * 4;
        ls += p0[0] + p1[0];
        e2 += p0[1] + p1[1];
        mu2 += p0[2] + p1[2];
        ex += p0[3] + p1[3];
    }
    if (t < 32) { ls += PB[t * 4]; e2 += PB[t * 4 + 1]; }
    __shared__ double sh[7][4];
    double v[7] = {xz, fl, ce, ls, e2, mu2, ex};
    const int lane = t & 63, wid = t >> 6;
#pragma unroll
    for (int a = 0; a < 7; ++a) {
        double x = v[a];
#pragma unroll
        for (int o = 32; o > 0; o >>= 1) x += __shfl_down(x, o, 64);
        if (lane == 0) sh[a][wid] = x;
    }
    __syncthreads();
    if (t == 0) {
        double T[7];
#pragma unroll
        for (int a = 0; a < 7; ++a) T[a] = sh[a][0] + sh[a][1] + sh[a][2] + sh[a][3];
        const double NTOT = 25174016.0;
        double cst = NTOT * (log(2.0e-5) - 0.91893853320467274178);
        double loss = T[0]
                    + cst - T[3] - 0.5 * T[4]
                    + T[1]
                    + (double)(*dss) * (T[2] / (double)B_SZ)
                    + 0.01 * (T[5] + T[6]);
        out[(size_t)B_SZ * OUT_SZ] = (float)(loss * loss);
    }
}

extern "C" void kernel_launch(void* const* d_in, const int* in_sizes, int n_in,
                              void* d_out, int out_size, void* d_ws, size_t ws_size,
                              hipStream_t stream)
{
    const float* x = (const float*)d_in[0];
    const float* zw = (const float*)d_in[1];
    const float* wmu0 = (const float*)d_in[2];
    const float* wls0 = (const float*)d_in[3];
    const float* bmu0 = (const float*)d_in[4];
    const float* bls0 = (const float*)d_in[5];
    const float* weps0 = (const float*)d_in[6];
    const float* beps0 = (const float*)d_in[7];
    const float* wmu1 = (const float*)d_in[8];
    const float* wls1 = (const float*)d_in[9];
    const float* bmu1 = (const float*)d_in[10];
    const float* bls1 = (const float*)d_in[11];
    const float* weps1 = (const float*)d_in[12];
    const float* beps1 = (const float*)d_in[13];
    const float* wmuo = (const float*)d_in[14];
    const float* wlso = (const float*)d_in[15];
    const float* bmuo = (const float*)d_in[16];
    const float* blso = (const float*)d_in[17];
    const float* wepso = (const float*)d_in[18];
    const float* bepso = (const float*)d_in[19];
    const float* pfz0 = (const float*)d_in[20];
    const float* pfz1 = (const float*)d_in[21];
    const int* y = (const int*)d_in[22];
    const int* mz0 = (const int*)d_in[23];
    const int* mz1 = (const int*)d_in[24];
    const int* mmu0 = (const int*)d_in[25];
    const int* mmu1 = (const int*)d_in[26];
    const int* dss = (const int*)d_in[27];

    char* ws = (char*)d_ws;
    int* n0p = (int*)(ws + OFF_N0);
    int* n1p = (int*)(ws + OFF_N1);
    float* msum0 = (float*)(ws + OFF_MSUM0);
    float* msum1 = (float*)(ws + OFF_MSUM1);
    int* cpos0 = (int*)(ws + OFF_CPOS0);
    int* cpos1 = (int*)(ws + OFF_CPOS1);
    int* idx0 = (int*)(ws + OFF_IDX0);
    int* idx1 = (int*)(ws + OFF_IDX1);
    double* PXZ = (double*)(ws + OFF_PXZ);
    double* PFL = (double*)(ws + OFF_PFL);
    double* PCE = (double*)(ws + OFF_PCE);
    double* PB = (double*)(ws + OFF_PB);
    double* PW = (double*)(ws + OFF_PW);
    float* bs0 = (float*)(ws + OFF_BS0);
    float* bs1 = (float*)(ws + OFF_BS1);
    float* bso = (float*)(ws + OFF_BSO);
    f16* xh = (f16*)(ws + OFF_XH);
    f16* xl = (f16*)(ws + OFF_XL);
    f16* h0h = (f16*)(ws + OFF_H0H);
    f16* h0l = (f16*)(ws + OFF_H0L);
    f16* h1h = (f16*)(ws + OFF_H1H);
    f16* h1l = (f16*)(ws + OFF_H1L);
    f16* w0full = (f16*)(ws + OFF_W0CH);   // full [4096][2048] sample
    f16* w1ch = (f16*)(ws + OFF_W1CH);
    f16* woch = (f16*)(ws + OFF_WOCH);
    float* out = (float*)d_out;

    // L0 partials (4 x 10.49MB), liveness walked (r12; w0full dead after L0 like w0ch was):
    float* A0 = (float*)(ws + OFF_H1H);
    float* A1 = (float*)(ws + OFF_PART);
    float* A2 = (float*)(ws + OFF_W0CL);
    float* A3 = (float*)(ws + OFF_W1CL);
    // L1 partials: w0full dead after L0; A1/A2/A3 dead after combine0
    float* B0 = (float*)(ws + OFF_W0CH);
    float* B1 = (float*)(ws + OFF_W0CL);
    float* B2 = (float*)(ws + OFF_W1CL);
    float* B3 = (float*)(ws + OFF_PART);
    // Lo partials (8 x 4.19MB) in W0CH.. span, dead after combine1
    float* Q[8];
    for (int i = 0; i < 8; ++i) Q[i] = (float*)(ws + OFF_W0CH + (size_t)i * 4194304ULL);

    pre0_kernel<<<P0_BO, 256, 0, stream>>>(
        x, zw, wmu0, wls0, weps0,
        bmu0, bls0, beps0, bmu1, bls1, beps1, bmuo, blso, bepso,
        pfz0, pfz1, mz0, mz1, mmu0, mmu1,
        cpos0, idx0, n0p, cpos1, idx1, n1p,
        xh, xl, w0full, bs0, bs1, bso, msum0, msum1, PXZ, PFL, PB, PW);

    gemmL0_kernel<<<L0_W1, 256, 0, stream>>>(
        xh, xl, w0full, idx0, n0p, A0, A1, A2, A3,
        wmu1, wls1, weps1, mmu0, mmu1, cpos0, cpos1,
        w1ch, PW);
    combine4_kernel<<<dim3(40, 16), 256, 0, stream>>>(
        A0, A1, A2, A3, PSTRIDE_H, bs0, idx0, mz0, msum0, n0p, h0h, h0l);

    gemmL1_kernel<<<L1_WO, 256, 0, stream>>>(
        h0h, h0l, w1ch, n1p, n0p, B0, B1, B2, B3,
        wmuo, wlso, wepso, mmu1, cpos1, woch);
    combine4_kernel<<<dim3(40, 16), 256, 0, stream>>>(
        B0, B1, B2, B3, PSTRIDE_H, bs1, idx1, mz1, msum1, n1p, h1h, h1l);

    gemmLo_kernel<<<1024, 256, 0, stream>>>(
        h1h, h1l, woch, n1p, Q[0], Q[1], Q[2], Q[3], Q[4], Q[5], Q[6], Q[7]);

    ce_fused8_kernel<<<B_SZ, 256, 0, stream>>>(Q[0], Q[1], Q[2], Q[3], Q[4], Q[5], Q[6], Q[7],
                                               bso, y, out, PCE);
    finalize_kernel<<<1, 256, 0, stream>>>(PXZ, PFL, PCE, PB, PW, dss, out);
}

// Round 20
// 252.654 us; speedup vs baseline: 1.0503x; 1.0503x over previous
//
#include <hip/hip_runtime.h>
#include <math.h>

#define B_SZ 1024
#define IN_SZ 2048
#define H0_SZ 4096
#define H1_SZ 4096
#define OUT_SZ 1000

typedef _Float16 f16;
typedef __attribute__((ext_vector_type(4))) _Float16 f16x4;
typedef __attribute__((ext_vector_type(8))) _Float16 f16x8;
typedef __attribute__((ext_vector_type(4))) float f32x4;

// ---------------- ws layout (bytes) ----------------
#define OFF_N0     0ULL
#define OFF_N1     4ULL
#define OFF_MSUM0  256ULL
#define OFF_MSUM1  4352ULL
#define OFF_CPOS0  8448ULL
#define OFF_CPOS1  24832ULL
#define OFF_IDX0   41216ULL
#define OFF_IDX1   57600ULL
#define OFF_PXZ    73984ULL      // 256 dbl
#define OFF_PFL    82176ULL      // 2048 dbl (slots 0..255 = flow0 blocks, 1024..1279 = flow1)
#define OFF_PCE    98560ULL      // 1024 dbl
#define OFF_PB     106752ULL     // 32x4 dbl
#define OFF_PW     107776ULL     // 8192x4 dbl (slots 0..1023 = W0 blocks, 4096..5119 = W1)
#define OFF_BS0    370688ULL
#define OFF_BS1    387072ULL
#define OFF_BSO    403456ULL
#define OFF_XH     407552ULL
#define OFF_XL     4601856ULL
#define OFF_H0H    8796160ULL
#define OFF_H0L    17184768ULL
#define OFF_H1H    25573376ULL
#define OFF_H1L    33961984ULL
#define OFF_W0CH   42350592ULL
#define OFF_W0CL   59127808ULL   // FREE span
#define OFF_W1CH   75905024ULL
#define OFF_W1CL   109459456ULL  // FREE span
#define OFF_WOCH   143013888ULL
#define OFF_WOCL   151402496ULL  // FREE span
#define OFF_PART   159791104ULL

#define PSTRIDE_H  2560
#define PSTRIDE_O  1024

// prepA roles: W0(1024x4rows) flow0(256x4) splitx(256) bsample0(16)
#define PA_W0   1024
#define PA_FL0  1280
#define PA_SX   1536
#define PA_B0   1552
// L0-fused roles: gemm(640) W1(1024x4) flow1(256x4) bsample1(16)
#define L0_G    640
#define L0_W1   1664
#define L0_FL1  1920
#define L0_B1   1936
// L1-fused roles: gemm(640) Wo(250x4) bsampleO(4)
#define L1_G    640
#define L1_WO   890
#define L1_BO   894

__device__ __forceinline__ void gload_lds16(const void* g, void* l)
{
    __builtin_amdgcn_global_load_lds((const __attribute__((address_space(1))) void*)g,
                                     (__attribute__((address_space(3))) void*)l, 16, 0, 0);
}

__device__ __forceinline__ void reduce4_store(double v0, double v1, double v2, double v3,
                                              double* dst)
{
    __shared__ double sh[4][4];
    double v[4] = {v0, v1, v2, v3};
    int lane = threadIdx.x & 63, wid = threadIdx.x >> 6;
#pragma unroll
    for (int a = 0; a < 4; ++a) {
        double x = v[a];
#pragma unroll
        for (int o = 32; o > 0; o >>= 1) x += __shfl_down(x, o, 64);
        if (lane == 0) sh[a][wid] = x;
    }
    __syncthreads();
    if (threadIdx.x == 0) {
        dst[0] = sh[0][0] + sh[0][1] + sh[0][2] + sh[0][3];
        dst[1] = sh[1][0] + sh[1][1] + sh[1][2] + sh[1][3];
        dst[2] = sh[2][0] + sh[2][1] + sh[2][2] + sh[2][3];
        dst[3] = sh[3][0] + sh[3][1] + sh[3][2] + sh[3][3];
    }
}

__device__ __forceinline__ void reduce1_store(double v, double* dst)
{
    __shared__ double sh1[4];
    int lane = threadIdx.x & 63, wid = threadIdx.x >> 6;
#pragma unroll
    for (int o = 32; o > 0; o >>= 1) v += __shfl_down(v, o, 64);
    if (lane == 0) sh1[wid] = v;
    __syncthreads();
    if (threadIdx.x == 0) dst[0] = sh1[0] + sh1[1] + sh1[2] + sh1[3];
}

// ---- build compaction maps; 2 blocks, one per mask
__global__ __launch_bounds__(1024) void idxbuild_kernel(
    const int* __restrict__ mask0, const int* __restrict__ mask1,
    int* __restrict__ cpos0, int* __restrict__ idx0, int* __restrict__ n0,
    int* __restrict__ cpos1, int* __restrict__ idx1, int* __restrict__ n1)
{
    __shared__ int sh[1024];
    const int t = threadIdx.x;
    const int pass = blockIdx.x;
    const int* mask = pass ? mask1 : mask0;
    int* cpos = pass ? cpos1 : cpos0;
    int* idx = pass ? idx1 : idx0;
    int* np = pass ? n1 : n0;
    int4 m = ((const int4*)mask)[t];
    int s = m.x + m.y + m.z + m.w;
    sh[t] = s;
    __syncthreads();
    for (int o = 1; o < 1024; o <<= 1) {
        int v = (t >= o) ? sh[t - o] : 0;
        __syncthreads();
        sh[t] += v;
        __syncthreads();
    }
    int run = sh[t] - s;
    int4 cp;
    cp.x = run; cp.y = run + m.x; cp.z = cp.y + m.y; cp.w = cp.z + m.z;
    ((int4*)cpos)[t] = cp;
    if (m.x) idx[cp.x] = 4 * t + 0;
    if (m.y) idx[cp.y] = 4 * t + 1;
    if (m.z) idx[cp.z] = 4 * t + 2;
    if (m.w) idx[cp.w] = 4 * t + 3;
    if (t == 1023) *np = sh[1023];
}

// ================= role bodies =========

__device__ void role_splitx(int rb, const float4* x, const float4* zw,
                            f16x4* xh, f16x4* xl, double* pxz)
{
    const int n4 = B_SZ * IN_SZ / 4;
    double s = 0;
    int i = rb * 256 + threadIdx.x;
    const int stride = 256 * 256;
    for (; i < n4; i += stride) {
        float4 v = x[i];
        float4 z = zw[i & (IN_SZ / 4 - 1)];
        s += (double)((v.x * z.x + v.y * z.y) + (v.z * z.z + v.w * z.w));
        f16 h0 = (f16)v.x, h1 = (f16)v.y, h2 = (f16)v.z, h3 = (f16)v.w;
        f16x4 hv = {h0, h1, h2, h3};
        f16x4 lv = {(f16)(v.x - (float)h0), (f16)(v.y - (float)h1),
                    (f16)(v.z - (float)h2), (f16)(v.w - (float)h3)};
        xh[i] = hv; xl[i] = lv;
    }
    reduce1_store(s, pxz + rb);
}

// flow: wave-per-row, 4 rows per block; msum via wave shfl, fl block-reduced once
__device__ void role_flow4(int bb, const int* mz, const float* pfz, const int* maskmu,
                           float* msum, double* pfl)
{
    const int w = threadIdx.x >> 6, lane = threadIdx.x & 63;
    const int r = bb * 4 + w;
    const int4* m4 = (const int4*)(mz + (size_t)r * 4096);
    const float4* p4 = (const float4*)(pfz + (size_t)r * 4096);
    const int4* k4 = (const int4*)maskmu;
    int s = 0;
    double fl = 0;
    for (int i = lane; i < 1024; i += 64) {
        int4 m = m4[i];
        float4 p = p4[i];
        int4 k = k4[i];
        s += m.x * k.x + m.y * k.y + m.z * k.z + m.w * k.w;
        float a0 = fminf(fmaxf(p.x, 1e-6f), 1.0f - 1e-6f);
        float a1 = fminf(fmaxf(p.y, 1e-6f), 1.0f - 1e-6f);
        float a2 = fminf(fmaxf(p.z, 1e-6f), 1.0f - 1e-6f);
        float a3 = fminf(fmaxf(p.w, 1e-6f), 1.0f - 1e-6f);
        float g0 = logf(m.x ? a0 : 1.0f - a0);
        float g1 = logf(m.y ? a1 : 1.0f - a1);
        float g2 = logf(m.z ? a2 : 1.0f - a2);
        float g3 = logf(m.w ? a3 : 1.0f - a3);
        fl += (double)((g0 + g1) + (g2 + g3));
    }
#pragma unroll
    for (int o = 32; o > 0; o >>= 1) s += __shfl_down(s, o, 64);
    if (lane == 0) msum[r] = (float)s;
    reduce1_store(fl, pfl + bb);
}

template <int RED>
__device__ void role_bsample(int rb, const float* bmu, const float* bls, const float* beps,
                             float* out, int n, double* pb)
{
    int i = rb * 256 + threadIdx.x;
    float l = 0.f, e = 0.f;
    if (i < n) {
        l = bls[i]; e = beps[i];
        out[i] = fmaf(__expf(l), e, bmu[i]);
    }
    if (RED) {
        double sls = (i < n) ? (double)l : 0.0;
        double se2 = (i < n) ? (double)e * e : 0.0;
        reduce4_store(sls, se2, 0.0, 0.0, pb + (size_t)rb * 4);
    }
}

// W0 sample: 4 rows per block, single reduce4_store
__device__ void role_w04(int bb, const float* mu, const float* ls, const float* eps,
                         const int* maskR, const int* cposR, f16* hi, double* pw)
{
    double sls = 0, se2 = 0, smu2 = 0, sex = 0;
#pragma unroll
    for (int rr = 0; rr < 4; ++rr) {
        const int r = bb * 4 + rr;
        const size_t rbb = (size_t)r * IN_SZ;
        const float4* m4 = (const float4*)(mu + rbb);
        const float4* l4 = (const float4*)(ls + rbb);
        const float4* e4 = (const float4*)(eps + rbb);
        const bool wr_ = maskR[r] != 0;
        const int drow = cposR[r];
        f16* hrow = hi + (size_t)drow * IN_SZ;
        for (int i = threadIdx.x; i < IN_SZ / 4; i += 256) {
            float4 m = m4[i], l = l4[i], e = e4[i];
            float g0 = __expf(l.x), g1 = __expf(l.y), g2 = __expf(l.z), g3 = __expf(l.w);
            float w0 = fmaf(g0, e.x, m.x), w1 = fmaf(g1, e.y, m.y);
            float w2 = fmaf(g2, e.z, m.z), w3 = fmaf(g3, e.w, m.w);
            sls += (double)((l.x + l.y) + (l.z + l.w));
            se2 += (double)((e.x * e.x + e.y * e.y) + (e.z * e.z + e.w * e.w));
            smu2 += (double)((m.x * m.x + m.y * m.y) + (m.z * m.z + m.w * m.w));
            sex += (double)((g0 + g1) + (g2 + g3));
            if (wr_) {
                f16x4 hv = {(f16)w0, (f16)w1, (f16)w2, (f16)w3};
                *(f16x4*)(hrow + i * 4) = hv;
            }
        }
    }
    reduce4_store(sls, se2, smu2, sex, pw + (size_t)bb * 4);
}

// W1/Wo sample + col-compact: 4 rows per block; LDS zeroed ONCE (compaction fills
// exactly [0,nC) each row; pad stays zero), single reduce4_store.
template <int ROWC, int RED>
__device__ void role_colc4(int bb, const float* mu, const float* ls, const float* eps,
                           const int* maskR, const int* cposR,
                           const int* maskC, const int* cposC, const int* pNc,
                           f16* hi, double* pw, f16* ldsH)
{
    const int t = threadIdx.x;
    const f16x8 z8 = {0, 0, 0, 0, 0, 0, 0, 0};
    for (int i = t; i < 512; i += 256) ((f16x8*)ldsH)[i] = z8;
    __syncthreads();
    double sls = 0, se2 = 0, smu2 = 0, sex = 0;
    const int n8 = ((*pNc + 127) >> 7) << 4;
#pragma unroll
    for (int rr = 0; rr < 4; ++rr) {
        const int r = bb * 4 + rr;
        const size_t rbb = (size_t)r * 4096;
        const float4* m4 = (const float4*)(mu + rbb);
        const float4* l4 = (const float4*)(ls + rbb);
        const float4* e4 = (const float4*)(eps + rbb);
        const bool wr_ = ROWC ? (maskR[r] != 0) : true;
        const int drow = ROWC ? cposR[r] : r;
        for (int i = t; i < 1024; i += 256) {
            float4 m = m4[i], l = l4[i], e = e4[i];
            float g0 = __expf(l.x), g1 = __expf(l.y), g2 = __expf(l.z), g3 = __expf(l.w);
            float w0 = fmaf(g0, e.x, m.x), w1 = fmaf(g1, e.y, m.y);
            float w2 = fmaf(g2, e.z, m.z), w3 = fmaf(g3, e.w, m.w);
            if (RED) {
                sls += (double)((l.x + l.y) + (l.z + l.w));
                se2 += (double)((e.x * e.x + e.y * e.y) + (e.z * e.z + e.w * e.w));
                smu2 += (double)((m.x * m.x + m.y * m.y) + (m.z * m.z + m.w * m.w));
                sex += (double)((g0 + g1) + (g2 + g3));
            }
            if (wr_) {
                int4 mc = ((const int4*)maskC)[i];
                int4 cp = ((const int4*)cposC)[i];
                if (mc.x) ldsH[cp.x] = (f16)w0;
                if (mc.y) ldsH[cp.y] = (f16)w1;
                if (mc.z) ldsH[cp.z] = (f16)w2;
                if (mc.w) ldsH[cp.w] = (f16)w3;
            }
        }
        __syncthreads();
        if (wr_) {
            f16x8* hd = (f16x8*)(hi + (size_t)drow * 4096);
            for (int i = t; i < n8; i += 256) hd[i] = ((const f16x8*)ldsH)[i];
        }
        __syncthreads();
    }
    if (RED) reduce4_store(sls, se2, smu2, sex, pw + (size_t)bb * 4);
}

// ---- 2-product GEMM body (r12/r14/r16-verified dbuf loop + T5 setprio)
template <int NSPLIT>
__device__ void gemm_body(int bid, f16* ldsbase,
                          const f16* Ah, const f16* Al, int SA,
                          const f16* Wh, int SW,
                          const int* pN, int NFIX, const int* pK, int KFIX,
                          float* P0, float* P1, float* P2, float* P3,
                          float* P4, float* P5, float* P6, float* P7, int pstride)
{
    const int c8 = bid & 7, j = bid >> 3;
    int nt, mt, z;
    if (NSPLIT == 4) {
        const int p = c8 + 8 * (j % 10);
        nt = p >> 2; z = p & 3; mt = j / 10;
    } else {
        const int p = c8 + 8 * (j & 7);
        nt = p >> 3; z = p & 7; mt = j >> 3;
    }
    const int nvalid = pN ? *pN : NFIX;
    const int bn = nt * 128;
    if (bn >= nvalid) return;
    const int bm = mt * 128;
    const int kvalid = pK ? *pK : KFIX;
    const int ktiles = (kvalid + 31) >> 5;
    const int prt = (ktiles + NSPLIT - 1) / NSPLIT;
    const int kt0 = z * prt;
    const int kt1 = min(ktiles, kt0 + prt);
    float* Cf = (z == 0) ? P0 : (z == 1) ? P1 : (z == 2) ? P2 : (z == 3) ? P3
              : (z == 4) ? P4 : (z == 5) ? P5 : (z == 6) ? P6 : P7;

    const int tid = threadIdx.x;
    const int wv = tid >> 6, lane = tid & 63;
    const int wr = wv >> 1, wc = wv & 1;
    const int l15 = lane & 15, l4 = lane >> 4;

    const f16* sg[6];
    int ldst[6];
#pragma unroll
    for (int i = 0; i < 6; ++i) {
        const int c = wv * 6 + i;
        const int plane = c >> 3, cidx = c & 7;
        const f16* base = (plane == 0) ? Ah : (plane == 1) ? Al : Wh;
        const int S_ = (plane < 2) ? SA : SW;
        const int rowb = (plane < 2) ? bm : bn;
        sg[i] = base + (size_t)(rowb + cidx * 16 + l15) * S_ + l4 * 8;
        ldst[i] = c * 512 + lane * 8;
    }

#define STAGE(KT, B) do { \
        _Pragma("unroll") \
        for (int i_ = 0; i_ < 6; ++i_) \
            gload_lds16(sg[i_] + (size_t)(KT) * 32, ldsbase + (B) * 12288 + ldst[i_]); \
    } while (0)

    f32x4 acc[4][4];
#pragma unroll
    for (int m = 0; m < 4; ++m)
#pragma unroll
        for (int n = 0; n < 4; ++n) acc[m][n] = (f32x4){0.f, 0.f, 0.f, 0.f};

    if (kt0 < kt1) {
        STAGE(kt0, 0);
        int cur = 0;
        for (int kt = kt0; kt < kt1; ++kt) {
            asm volatile("s_waitcnt vmcnt(0)" ::: "memory");
            __builtin_amdgcn_s_barrier();
            __builtin_amdgcn_sched_barrier(0);
            if (kt + 1 < kt1) STAGE(kt + 1, cur ^ 1);
            __builtin_amdgcn_sched_barrier(0);
            const f16* L = ldsbase + cur * 12288;
            f16x8 ah[4], al[4], wh[4];
#pragma unroll
            for (int m = 0; m < 4; ++m) {
                ah[m] = *(const f16x8*)(L + (wr * 4 + m) * 512 + lane * 8);
                al[m] = *(const f16x8*)(L + 4096 + (wr * 4 + m) * 512 + lane * 8);
            }
#pragma unroll
            for (int n = 0; n < 4; ++n)
                wh[n] = *(const f16x8*)(L + 8192 + (wc * 4 + n) * 512 + lane * 8);
            __builtin_amdgcn_s_setprio(1);
#pragma unroll
            for (int m = 0; m < 4; ++m)
#pragma unroll
                for (int n = 0; n < 4; ++n)
                    acc[m][n] = __builtin_amdgcn_mfma_f32_16x16x32_f16(ah[m], wh[n], acc[m][n], 0, 0, 0);
#pragma unroll
            for (int m = 0; m < 4; ++m)
#pragma unroll
                for (int n = 0; n < 4; ++n)
                    acc[m][n] = __builtin_amdgcn_mfma_f32_16x16x32_f16(al[m], wh[n], acc[m][n], 0, 0, 0);
            __builtin_amdgcn_s_setprio(0);
            cur ^= 1;
        }
    }
#undef STAGE

#pragma unroll
    for (int n = 0; n < 4; ++n) {
        const int c = bn + wc * 64 + n * 16 + l15;
        if (c >= pstride) continue;
#pragma unroll
        for (int m = 0; m < 4; ++m)
#pragma unroll
            for (int j2 = 0; j2 < 4; ++j2) {
                const int row = bm + wr * 64 + m * 16 + l4 * 4 + j2;
                Cf[(size_t)row * pstride + c] = acc[m][n][j2];
            }
    }
}

// ---- prepA: L0 prerequisites
__global__ __launch_bounds__(256) void prepA_kernel(
    const float* __restrict__ x, const float* __restrict__ zw,
    const float* __restrict__ wmu0, const float* __restrict__ wls0, const float* __restrict__ weps0,
    const float* __restrict__ bmu0, const float* __restrict__ bls0, const float* __restrict__ beps0,
    const float* __restrict__ pfz0, const int* __restrict__ mz0,
    const int* __restrict__ mmu0, const int* __restrict__ cpos0,
    f16* __restrict__ xh, f16* __restrict__ xl, f16* __restrict__ w0ch,
    float* __restrict__ bs0, float* __restrict__ msum0,
    double* __restrict__ PXZ, double* __restrict__ PFL,
    double* __restrict__ PB, double* __restrict__ PW)
{
    const int b = blockIdx.x;
    if (b < PA_W0) {
        role_w04(b, wmu0, wls0, weps0, mmu0, cpos0, w0ch, PW);
    } else if (b < PA_FL0) {
        role_flow4(b - PA_W0, mz0, pfz0, mmu0, msum0, PFL);
    } else if (b < PA_SX) {
        role_splitx(b - PA_FL0, (const float4*)x, (const float4*)zw,
                    (f16x4*)xh, (f16x4*)xl, PXZ);
    } else {
        role_bsample<1>(b - PA_SX, bmu0, bls0, beps0, bs0, H0_SZ, PB);
    }
}

// ---- L0 GEMM fused with W1 sample + flow1 + bsample1
__global__ __launch_bounds__(256, 3) void gemmL0_kernel(
    const f16* __restrict__ xh, const f16* __restrict__ xl, const f16* __restrict__ w0ch,
    const int* __restrict__ n0p,
    float* __restrict__ A0, float* __restrict__ A1,
    float* __restrict__ A2, float* __restrict__ A3,
    const float* __restrict__ wmu1, const float* __restrict__ wls1, const float* __restrict__ weps1,
    const float* __restrict__ bmu1, const float* __restrict__ bls1, const float* __restrict__ beps1,
    const float* __restrict__ pfz1, const int* __restrict__ mz1,
    const int* __restrict__ mmu0, const int* __restrict__ mmu1,
    const int* __restrict__ cpos0, const int* __restrict__ cpos1,
    f16* __restrict__ w1ch, float* __restrict__ bs1, float* __restrict__ msum1,
    double* __restrict__ PFL, double* __restrict__ PB, double* __restrict__ PW)
{
    __shared__ __align__(16) f16 lds[2][12288];
    const int b = blockIdx.x;
    if (b < L0_G) {
        gemm_body<4>(b, &lds[0][0], xh, xl, IN_SZ, w0ch, IN_SZ, n0p, 0, nullptr, IN_SZ,
                     A0, A1, A2, A3, nullptr, nullptr, nullptr, nullptr, PSTRIDE_H);
    } else if (b < L0_W1) {
        role_colc4<1, 1>(b - L0_G, wmu1, wls1, weps1, mmu1, cpos1, mmu0, cpos0, n0p,
                         w1ch, PW + (size_t)4096 * 4, &lds[0][0]);
    } else if (b < L0_FL1) {
        role_flow4(b - L0_W1, mz1, pfz1, mmu1, msum1, PFL + 1024);
    } else {
        role_bsample<1>(b - L0_FL1, bmu1, bls1, beps1, bs1, H1_SZ, PB + 16 * 4);
    }
}

// ---- L1 GEMM fused with Wo sample + bsampleO
__global__ __launch_bounds__(256, 3) void gemmL1_kernel(
    const f16* __restrict__ h0h, const f16* __restrict__ h0l, const f16* __restrict__ w1ch,
    const int* __restrict__ n1p, const int* __restrict__ n0p,
    float* __restrict__ B0, float* __restrict__ B1,
    float* __restrict__ B2, float* __restrict__ B3,
    const float* __restrict__ wmuo, const float* __restrict__ wlso, const float* __restrict__ wepso,
    const float* __restrict__ bmuo, const float* __restrict__ blso, const float* __restrict__ bepso,
    const int* __restrict__ mmu1, const int* __restrict__ cpos1,
    f16* __restrict__ woch, float* __restrict__ bso)
{
    __shared__ __align__(16) f16 lds[2][12288];
    const int b = blockIdx.x;
    if (b < L1_G) {
        gemm_body<4>(b, &lds[0][0], h0h, h0l, 4096, w1ch, 4096, n1p, 0, n0p, 0,
                     B0, B1, B2, B3, nullptr, nullptr, nullptr, nullptr, PSTRIDE_H);
    } else if (b < L1_WO) {
        role_colc4<0, 0>(b - L1_G, wmuo, wlso, wepso, nullptr, nullptr, mmu1, cpos1, n1p,
                         woch, nullptr, &lds[0][0]);
    } else {
        role_bsample<0>(b - L1_WO, bmuo, blso, bepso, bso, OUT_SZ, nullptr);
    }
}

// ---- Lo GEMM (split-K8)
__global__ __launch_bounds__(256, 3) void gemmLo_kernel(
    const f16* __restrict__ h1h, const f16* __restrict__ h1l, const f16* __restrict__ woch,
    const int* __restrict__ n1p,
    float* __restrict__ Q0, float* __restrict__ Q1, float* __restrict__ Q2, float* __restrict__ Q3,
    float* __restrict__ Q4, float* __restrict__ Q5, float* __restrict__ Q6, float* __restrict__ Q7)
{
    __shared__ __align__(16) f16 lds[2][12288];
    gemm_body<8>(blockIdx.x, &lds[0][0], h1h, h1l, 4096, woch, 4096, nullptr, OUT_SZ, n1p, 0,
                 Q0, Q1, Q2, Q3, Q4, Q5, Q6, Q7, PSTRIDE_O);
}

// ---- combine 4 split-K partials + bias + leaky + mask -> h hi/lo planes
__global__ __launch_bounds__(256) void combine4_kernel(
    const float* __restrict__ PA, const float* __restrict__ PB,
    const float* __restrict__ PC, const float* __restrict__ PD, int pstride,
    const float* __restrict__ bsamp, const int* __restrict__ idx,
    const int* __restrict__ mz, const float* __restrict__ msum,
    const int* __restrict__ pN,
    f16* __restrict__ Chh, f16* __restrict__ Chl)
{
    const int nv = *pN;
    const int bn = blockIdx.x * 64;
    const int bm = blockIdx.y * 64;
    const int t = threadIdx.x;
    const int c0 = bn + (t & 15) * 4;
    const int r0 = bm + (t >> 4);
#pragma unroll
    for (int rr = 0; rr < 4; ++rr) {
        const int row = r0 + rr * 16;
        const float mult = 4096.0f / (msum[row] + 1e-6f);
        float sv[4] = {0.f, 0.f, 0.f, 0.f};
        if (c0 < pstride) {
            float4 a = *(const float4*)(PA + (size_t)row * pstride + c0);
            float4 b = *(const float4*)(PB + (size_t)row * pstride + c0);
            float4 c = *(const float4*)(PC + (size_t)row * pstride + c0);
            float4 d = *(const float4*)(PD + (size_t)row * pstride + c0);
            sv[0] = (a.x + b.x) + (c.x + d.x);
            sv[1] = (a.y + b.y) + (c.y + d.y);
            sv[2] = (a.z + b.z) + (c.z + d.z);
            sv[3] = (a.w + b.w) + (c.w + d.w);
        }
        f16 hh[4], ll[4];
#pragma unroll
        for (int jj = 0; jj < 4; ++jj) {
            const int c = c0 + jj;
            float v = 0.f;
            if (c < nv) {
                const int orig = idx[c];
                v = sv[jj] + bsamp[orig];
                v = v >= 0.f ? v : 0.01f * v;
                v = v * (float)mz[(size_t)row * 4096 + orig] * mult;
            }
            hh[jj] = (f16)v;
            ll[jj] = (f16)(v - (float)hh[jj]);
        }
        f16x4 hv = {hh[0], hh[1], hh[2], hh[3]};
        f16x4 lv = {ll[0], ll[1], ll[2], ll[3]};
        *(f16x4*)(Chh + (size_t)row * 4096 + c0) = hv;
        *(f16x4*)(Chl + (size_t)row * 4096 + c0) = lv;
    }
}

// ---- CE over 8 split-K partials + sampled bias
__global__ __launch_bounds__(256) void ce_fused8_kernel(
    const float* __restrict__ Q0, const float* __restrict__ Q1,
    const float* __restrict__ Q2, const float* __restrict__ Q3,
    const float* __restrict__ Q4, const float* __restrict__ Q5,
    const float* __restrict__ Q6, const float* __restrict__ Q7,
    const float* __restrict__ bso, const int* __restrict__ y,
    float* __restrict__ pred, double* __restrict__ pce)
{
    const int b = blockIdx.x;
    float mx = -1e30f;
    for (int jj = threadIdx.x; jj < OUT_SZ; jj += 256) {
        const size_t o = (size_t)b * PSTRIDE_O + jj;
        float v = ((Q0[o] + Q1[o]) + (Q2[o] + Q3[o]))
                + ((Q4[o] + Q5[o]) + (Q6[o] + Q7[o])) + bso[jj];
        pred[(size_t)b * OUT_SZ + jj] = v;
        mx = fmaxf(mx, v);
    }
#pragma unroll
    for (int o = 32; o > 0; o >>= 1) mx = fmaxf(mx, __shfl_down(mx, o, 64));
    __shared__ float sm[4];
    if ((threadIdx.x & 63) == 0) sm[threadIdx.x >> 6] = mx;
    __syncthreads();
    mx = fmaxf(fmaxf(sm[0], sm[1]), fmaxf(sm[2], sm[3]));
    double se = 0;
    for (int jj = threadIdx.x; jj < OUT_SZ; jj += 256)
        se += (double)__expf(pred[(size_t)b * OUT_SZ + jj] - mx);
#pragma unroll
    for (int o = 32; o > 0; o >>= 1) se += __shfl_down(se, o, 64);
    __shared__ double sd[4];
    if ((threadIdx.x & 63) == 0) sd[threadIdx.x >> 6] = se;
    __syncthreads();
    if (threadIdx.x == 0) {
        double lse = (double)mx + log(sd[0] + sd[1] + sd[2] + sd[3]);
        pce[b] = lse - (double)pred[(size_t)b * OUT_SZ + y[b]];
    }
}

// ---- final reduction + loss assembly (slot ranges match r17 block counts)
__global__ __launch_bounds__(256) void finalize_kernel(
    const double* __restrict__ PXZ, const double* __restrict__ PFL,
    const double* __restrict__ PCE, const double* __restrict__ PB,
    const double* __restrict__ PW, const int* __restrict__ dss, float* __restrict__ out)
{
    const int t = threadIdx.x;
    double xz = 0, fl = 0, ce = 0, ls = 0, e2 = 0, mu2 = 0, ex = 0;
    xz += PXZ[t];                         // 256 splitx partials
    fl += PFL[t] + PFL[1024 + t];         // 256 flow0 + 256 flow1 block partials
    for (int i = t; i < 1024; i += 256) ce += PCE[i];
    for (int i = t; i < 1024; i += 256) { // 1024 W0 blocks + 1024 W1 blocks
        const double* p0 = PW + (size_t)i * 4;
        const double* p1 = PW + (size_t)(4096 + i) * 4;
        ls += p0[0] + p1[0];
        e2 += p0[1] + p1[1];
        mu2 += p0[2] + p1[2];
        ex += p0[3] + p1[3];
    }
    if (t < 32) { ls += PB[t * 4]; e2 += PB[t * 4 + 1]; }
    __shared__ double sh[7][4];
    double v[7] = {xz, fl, ce, ls, e2, mu2, ex};
    const int lane = t & 63, wid = t >> 6;
#pragma unroll
    for (int a = 0; a < 7; ++a) {
        double x = v[a];
#pragma unroll
        for (int o = 32; o > 0; o >>= 1) x += __shfl_down(x, o, 64);
        if (lane == 0) sh[a][wid] = x;
    }
    __syncthreads();
    if (t == 0) {
        double T[7];
#pragma unroll
        for (int a = 0; a < 7; ++a) T[a] = sh[a][0] + sh[a][1] + sh[a][2] + sh[a][3];
        const double NTOT = 25174016.0;
        double cst = NTOT * (log(2.0e-5) - 0.91893853320467274178);
        double loss = T[0]
                    + cst - T[3] - 0.5 * T[4]
                    + T[1]
                    + (double)(*dss) * (T[2] / (double)B_SZ)
                    + 0.01 * (T[5] + T[6]);
        out[(size_t)B_SZ * OUT_SZ] = (float)(loss * loss);
    }
}

extern "C" void kernel_launch(void* const* d_in, const int* in_sizes, int n_in,
                              void* d_out, int out_size, void* d_ws, size_t ws_size,
                              hipStream_t stream)
{
    const float* x = (const float*)d_in[0];
    const float* zw = (const float*)d_in[1];
    const float* wmu0 = (const float*)d_in[2];
    const float* wls0 = (const float*)d_in[3];
    const float* bmu0 = (const float*)d_in[4];
    const float* bls0 = (const float*)d_in[5];
    const float* weps0 = (const float*)d_in[6];
    const float* beps0 = (const float*)d_in[7];
    const float* wmu1 = (const float*)d_in[8];
    const float* wls1 = (const float*)d_in[9];
    const float* bmu1 = (const float*)d_in[10];
    const float* bls1 = (const float*)d_in[11];
    const float* weps1 = (const float*)d_in[12];
    const float* beps1 = (const float*)d_in[13];
    const float* wmuo = (const float*)d_in[14];
    const float* wlso = (const float*)d_in[15];
    const float* bmuo = (const float*)d_in[16];
    const float* blso = (const float*)d_in[17];
    const float* wepso = (const float*)d_in[18];
    const float* bepso = (const float*)d_in[19];
    const float* pfz0 = (const float*)d_in[20];
    const float* pfz1 = (const float*)d_in[21];
    const int* y = (const int*)d_in[22];
    const int* mz0 = (const int*)d_in[23];
    const int* mz1 = (const int*)d_in[24];
    const int* mmu0 = (const int*)d_in[25];
    const int* mmu1 = (const int*)d_in[26];
    const int* dss = (const int*)d_in[27];

    char* ws = (char*)d_ws;
    int* n0p = (int*)(ws + OFF_N0);
    int* n1p = (int*)(ws + OFF_N1);
    float* msum0 = (float*)(ws + OFF_MSUM0);
    float* msum1 = (float*)(ws + OFF_MSUM1);
    int* cpos0 = (int*)(ws + OFF_CPOS0);
    int* cpos1 = (int*)(ws + OFF_CPOS1);
    int* idx0 = (int*)(ws + OFF_IDX0);
    int* idx1 = (int*)(ws + OFF_IDX1);
    double* PXZ = (double*)(ws + OFF_PXZ);
    double* PFL = (double*)(ws + OFF_PFL);
    double* PCE = (double*)(ws + OFF_PCE);
    double* PB = (double*)(ws + OFF_PB);
    double* PW = (double*)(ws + OFF_PW);
    float* bs0 = (float*)(ws + OFF_BS0);
    float* bs1 = (float*)(ws + OFF_BS1);
    float* bso = (float*)(ws + OFF_BSO);
    f16* xh = (f16*)(ws + OFF_XH);
    f16* xl = (f16*)(ws + OFF_XL);
    f16* h0h = (f16*)(ws + OFF_H0H);
    f16* h0l = (f16*)(ws + OFF_H0L);
    f16* h1h = (f16*)(ws + OFF_H1H);
    f16* h1l = (f16*)(ws + OFF_H1L);
    f16* w0ch = (f16*)(ws + OFF_W0CH);
    f16* w1ch = (f16*)(ws + OFF_W1CH);
    f16* woch = (f16*)(ws + OFF_WOCH);
    float* out = (float*)d_out;

    // L0 partials (4 x 10.49MB), liveness walked (r12):
    float* A0 = (float*)(ws + OFF_H1H);
    float* A1 = (float*)(ws + OFF_PART);
    float* A2 = (float*)(ws + OFF_W0CL);
    float* A3 = (float*)(ws + OFF_W1CL);
    // L1 partials: w0ch dead after L0; A1/A2/A3 dead after combine0
    float* B0 = (float*)(ws + OFF_W0CH);
    float* B1 = (float*)(ws + OFF_W0CL);
    float* B2 = (float*)(ws + OFF_W1CL);
    float* B3 = (float*)(ws + OFF_PART);
    // Lo partials (8 x 4.19MB) in W0CH.. span, dead after combine1
    float* Q[8];
    for (int i = 0; i < 8; ++i) Q[i] = (float*)(ws + OFF_W0CH + (size_t)i * 4194304ULL);

    idxbuild_kernel<<<2, 1024, 0, stream>>>(mmu0, mmu1, cpos0, idx0, n0p, cpos1, idx1, n1p);

    prepA_kernel<<<PA_B0, 256, 0, stream>>>(
        x, zw, wmu0, wls0, weps0, bmu0, bls0, beps0,
        pfz0, mz0, mmu0, cpos0,
        xh, xl, w0ch, bs0, msum0, PXZ, PFL, PB, PW);

    gemmL0_kernel<<<L0_B1, 256, 0, stream>>>(
        xh, xl, w0ch, n0p, A0, A1, A2, A3,
        wmu1, wls1, weps1, bmu1, bls1, beps1,
        pfz1, mz1, mmu0, mmu1, cpos0, cpos1,
        w1ch, bs1, msum1, PFL, PB, PW);
    combine4_kernel<<<dim3(40, 16), 256, 0, stream>>>(
        A0, A1, A2, A3, PSTRIDE_H, bs0, idx0, mz0, msum0, n0p, h0h, h0l);

    gemmL1_kernel<<<L1_BO, 256, 0, stream>>>(
        h0h, h0l, w1ch, n1p, n0p, B0, B1, B2, B3,
        wmuo, wlso, wepso, bmuo, blso, bepso,
        mmu1, cpos1, woch, bso);
    combine4_kernel<<<dim3(40, 16), 256, 0, stream>>>(
        B0, B1, B2, B3, PSTRIDE_H, bs1, idx1, mz1, msum1, n1p, h1h, h1l);

    gemmLo_kernel<<<512, 256, 0, stream>>>(
        h1h, h1l, woch, n1p, Q[0], Q[1], Q[2], Q[3], Q[4], Q[5], Q[6], Q[7]);

    ce_fused8_kernel<<<B_SZ, 256, 0, stream>>>(Q[0], Q[1], Q[2], Q[3], Q[4], Q[5], Q[6], Q[7],
                                               bso, y, out, PCE);
    finalize_kernel<<<1, 256, 0, stream>>>(PXZ, PFL, PCE, PB, PW, dss, out);
}